// Round 12
// baseline (287.384 us; speedup 1.0000x reference)
//
#include <hip/hip_runtime.h>
#include <stdint.h>
#include <math.h>

// Problem constants (fixed by the reference)
#define NB    32          // graphs
#define NNODE 2048        // nodes per graph
#define NT    (NB*NNODE)  // 65536 total nodes
#define EPB   16384       // edges per graph
#define ETOT  (NB*EPB)    // 524288 edges
#define DF    128         // feature dim
#define KSEL  615         // ceil(0.3*2048)

typedef __attribute__((ext_vector_type(8))) short bf16x8;
typedef __attribute__((ext_vector_type(4))) float f32x4;

// ---- split-precision helpers: f32 ~= hi(bf16) + lo(bf16), err ~2^-17 ----
__device__ __forceinline__ unsigned short f2bf(float f){
  uint32_t u = __float_as_uint(f);
  u += 0x7FFFu + ((u>>16)&1u);                 // RNE
  return (unsigned short)(u>>16);
}
__device__ __forceinline__ void split2(float f, unsigned short& hi, unsigned short& lo){
  unsigned short h = f2bf(f);
  float fh = __uint_as_float(((uint32_t)h)<<16);
  hi = h;
  lo = f2bf(f - fh);
}
// monotone u32 <-> f32 (ascending u32 == ascending float over all reals)
__device__ __forceinline__ uint32_t f2mono(float f){
  uint32_t u = __float_as_uint(f);
  return (u & 0x80000000u) ? ~u : (u | 0x80000000u);
}
__device__ __forceinline__ float mono2f(uint32_t m){
  uint32_t u = (m & 0x80000000u) ? (m ^ 0x80000000u) : ~m;
  return __uint_as_float(u);
}

// ---------------- CSR build (global-atomic chain — proven fast) ------------
// blocks 0..2047: degree count (global atomics). blocks 2048..2079: packB.
__global__ void k_deg(const int* __restrict__ edst, uint32_t* __restrict__ deg,
                      const float* __restrict__ Wl1, const float* __restrict__ Wr1,
                      const float* __restrict__ Wl2, const float* __restrict__ Wr2,
                      unsigned short* __restrict__ Bpk){
  const int bid = blockIdx.x;
  if (bid < ETOT/256){
    int e = bid*256 + threadIdx.x;
    int g = e >> 14;                           // EPB = 2^14
    atomicAdd(&deg[g*NNODE + edst[e]], 1u);
  } else {
    // weight pack: Bpk elem offset ks*8192 + ct*1024 + part*512 + lane*8 + j
    int tt = (bid - ETOT/256)*256 + threadIdx.x;   // 0..8191
    int layer = tt >> 12;
    int t2 = tt & 4095;
    const float* Wl = layer ? Wl2 : Wl1;
    const float* Wr = layer ? Wr2 : Wr1;
    unsigned short* B = Bpk + (size_t)layer*65536;
    int lane = t2 & 63;
    int ct   = (t2>>6) & 7;
    int ks   = (t2>>9) & 7;
    int c  = ct*16 + (lane & 15);
    int k0 = ks*32 + ((lane>>4)<<3);
    size_t base = ((size_t)((ks*8+ct)*2)*64 + lane)*8;
    #pragma unroll
    for (int j=0;j<8;++j){
      int k = k0 + j;
      float v = (k < DF) ? Wl[c*DF + k] : Wr[c*DF + (k-DF)];
      unsigned short h, l; split2(v, h, l);
      B[base + j]       = h;
      B[base + 512 + j] = l;
    }
  }
}

__global__ __launch_bounds__(1024) void k_scan1(const uint32_t* __restrict__ deg,
                        uint32_t* __restrict__ rowptr, uint32_t* __restrict__ bsum){
  __shared__ uint32_t sh[1024];
  int t = threadIdx.x; int base = blockIdx.x*1024;
  uint32_t v = deg[base+t];
  sh[t] = v;
  for (int off=1; off<1024; off<<=1){
    __syncthreads();
    uint32_t a = (t>=off) ? sh[t-off] : 0u;
    __syncthreads();
    sh[t] += a;
  }
  rowptr[base+t] = sh[t] - v;
  if (t==1023) bsum[blockIdx.x] = sh[1023];
}

__global__ void k_scan2(uint32_t* __restrict__ bsum){
  __shared__ uint32_t sh[64];
  int t = threadIdx.x;
  uint32_t v = bsum[t]; sh[t] = v;
  for (int off=1; off<64; off<<=1){
    __syncthreads();
    uint32_t a = (t>=off) ? sh[t-off] : 0u;
    __syncthreads();
    sh[t] += a;
  }
  bsum[t] = sh[t] - v;
}

__global__ __launch_bounds__(1024) void k_scan3(uint32_t* __restrict__ rowptr,
                                                const uint32_t* __restrict__ bsum){
  int i = blockIdx.x*1024 + threadIdx.x;
  rowptr[i] += bsum[i>>10];
  if (i==0) rowptr[NT] = ETOT;
}

__global__ void k_scatter(const int* __restrict__ esrc, const int* __restrict__ edst,
                          const uint32_t* __restrict__ rowptr, uint32_t* __restrict__ deg,
                          int* __restrict__ col){
  int e = blockIdx.x*256 + threadIdx.x;
  int g = e >> 14;
  int d = g*NNODE + edst[e];
  int s = g*NNODE + esrc[e];
  uint32_t old = atomicSub(&deg[d], 1u);
  col[rowptr[d] + old - 1u] = s;
}

// ---------------- aggregation via whole-graph LDS slice --------------------
// One block per (graph, 16-feature slice): stage ALL 2048 source rows' 64B
// slices into LDS (one coalesced 128KB read — kills the 8x L2 re-fetch that
// made the fused gather MSHR-bound), then walk all 16384 edges reading from
// LDS. Subgroup = 4 lanes (q = feature quad), owns 16 contiguous CSR rows;
// 2-deep pipelined ds_read_b128; flush accumulator to AGG on row change.
// XCD swizzle: graph = bid&31 (all 8 slice-blocks of graph g on XCD g%8,
// so the 8x re-read of col[] is XCD-L2-hot).
__global__ __launch_bounds__(512) void k_aggX(
    const float* __restrict__ Xin, const uint32_t* __restrict__ rowptr,
    const int* __restrict__ col, float* __restrict__ AGG)
{
  extern __shared__ float Xs[];                // 2048*16 f32 = 128KB dynamic
  const int t = threadIdx.x;
  const int g = blockIdx.x & 31, sl = blockIdx.x >> 5;   // slice 0..7
  const int f0 = sl*16;
  const int gbase = g*NNODE;

  // ---- stage graph's 16-feature slice (coalesced) ----
  {
    const float4* Xg = (const float4*)(Xin + (size_t)gbase*DF + f0);
    #pragma unroll
    for (int i=0;i<16;++i){
      int idx = i*512 + t;
      int row = idx >> 2, q = idx & 3;
      float4 v = Xg[(size_t)row*32 + q];       // row stride 128 f32 = 32 f4
      *(float4*)&Xs[row*16 + q*4] = v;
    }
  }
  __syncthreads();

  // ---- edge walk from LDS ----
  const int sg = t >> 2, q = t & 3;            // 128 subgroups x 16 rows
  int cur = sg*16;
  const int curEnd = cur + 16;
  const uint32_t kb = rowptr[gbase + cur];
  const uint32_t ke = rowptr[gbase + curEnd];
  uint32_t rstart = kb;
  uint32_t rnext  = rowptr[gbase + cur + 1];
  f32x4 accv = {0.f,0.f,0.f,0.f};

  auto flush = [&](){
    uint32_t d = rnext - rstart;
    float invd = 1.0f / (float)(d ? d : 1u);
    *(f32x4*)(AGG + (size_t)(gbase+cur)*DF + f0 + q*4) = accv * invd;
    accv = (f32x4){0.f,0.f,0.f,0.f};
    cur++;
    rstart = rnext;
    rnext = (cur < curEnd) ? rowptr[gbase + cur + 1] : 0xFFFFFFFFu;
  };

  uint32_t e = kb;
  if (e < ke){
    int s = col[e] & (NNODE-1);
    f32x4 vcur = *(const f32x4*)&Xs[s*16 + q*4];
    while (true){
      uint32_t e2 = e + 1;
      f32x4 vnext = {0.f,0.f,0.f,0.f};
      bool more = (e2 < ke);
      if (more){
        int s2 = col[e2] & (NNODE-1);
        vnext = *(const f32x4*)&Xs[s2*16 + q*4];   // issued before accv use
      }
      while (rnext <= e) flush();
      accv += vcur;
      if (!more) break;
      vcur = vnext; e = e2;
    }
  }
  while (cur < curEnd) flush();                // trailing (incl. empty) rows
}

// ---------------- SAGE combine: split-bf16 MFMA from AGG + X ---------------
// 256 threads, 4 independent waves x 16 rows (64 rows/block, no LDS).
// All 16 A-operand loads issued up front; K=256: ks0-3 from AGG, ks4-7 from
// own row; 3 MFMAs (hi*hi+hi*lo+lo*hi) per (ct,ks). XCD swizzle: bid&31.
template<int LAYER>
__global__ __launch_bounds__(256) void k_comb(
    const float* __restrict__ AGG, const float* __restrict__ Xin,
    const unsigned short* __restrict__ Bpk, const float* __restrict__ bias,
    float* __restrict__ OUT, const float* __restrict__ pw,
    float* __restrict__ scores)
{
  const int t = threadIdx.x;
  const int g = blockIdx.x & 31, jb = blockIdx.x >> 5;   // 32 blocks/graph
  const int l = t & 63, wid = t >> 6;
  const int q = l >> 4, c16 = l & 15;
  const int rowBase = g*NNODE + jb*64;
  const int arow = rowBase + wid*16 + c16;

  f32x4 aggv[8], own[8];
  #pragma unroll
  for (int ks4=0; ks4<4; ++ks4){
    const float* a = AGG + (size_t)arow*DF + ks4*32 + q*8;
    aggv[ks4*2]   = *(const f32x4*)a;
    aggv[ks4*2+1] = *(const f32x4*)(a+4);
    const float* s = Xin + (size_t)arow*DF + ks4*32 + q*8;
    own[ks4*2]    = *(const f32x4*)s;
    own[ks4*2+1]  = *(const f32x4*)(s+4);
  }

  f32x4 acc[8];
  #pragma unroll
  for (int ct=0; ct<8; ++ct) acc[ct] = (f32x4){0.f,0.f,0.f,0.f};

  #pragma unroll
  for (int ks=0; ks<8; ++ks){
    f32x4 A0 = (ks<4) ? aggv[ks*2]   : own[(ks-4)*2];
    f32x4 A1 = (ks<4) ? aggv[ks*2+1] : own[(ks-4)*2+1];
    float v[8] = {A0.x,A0.y,A0.z,A0.w,A1.x,A1.y,A1.z,A1.w};
    bf16x8 ahi, alo;
    #pragma unroll
    for (int j=0;j<8;++j){
      unsigned short h, lo_; split2(v[j], h, lo_);
      ahi[j] = (short)h; alo[j] = (short)lo_;
    }
    const unsigned short* bp = Bpk + (size_t)ks*8192 + l*8;
    #pragma unroll
    for (int ct=0; ct<8; ++ct){
      bf16x8 bhi = *(const bf16x8*)(bp + ct*1024);
      bf16x8 blo = *(const bf16x8*)(bp + ct*1024 + 512);
      acc[ct] = __builtin_amdgcn_mfma_f32_16x16x32_bf16(ahi, bhi, acc[ct], 0,0,0);
      acc[ct] = __builtin_amdgcn_mfma_f32_16x16x32_bf16(ahi, blo, acc[ct], 0,0,0);
      acc[ct] = __builtin_amdgcn_mfma_f32_16x16x32_bf16(alo, bhi, acc[ct], 0,0,0);
    }
  }

  const int rowOut = rowBase + wid*16;
  if constexpr (LAYER==1){
    #pragma unroll
    for (int ct=0; ct<8; ++ct){
      int c = ct*16 + c16;
      float bv = bias[c];
      #pragma unroll
      for (int r=0; r<4; ++r){
        int grow = rowOut + q*4 + r;
        OUT[(size_t)grow*DF + c] = fmaxf(acc[ct][r] + bv, 0.f);
      }
    }
  } else {
    float ov[8][4];
    float pwv[8];
    float n2 = 0.f;
    #pragma unroll
    for (int ct=0; ct<8; ++ct){ pwv[ct] = pw[ct*16 + c16]; n2 += pwv[ct]*pwv[ct]; }
    n2 += __shfl_xor(n2,8,16); n2 += __shfl_xor(n2,4,16);
    n2 += __shfl_xor(n2,2,16); n2 += __shfl_xor(n2,1,16);
    float nrm = sqrtf(n2);
    #pragma unroll
    for (int ct=0; ct<8; ++ct){
      int c = ct*16 + c16;
      float bv = bias[c];
      #pragma unroll
      for (int r=0; r<4; ++r){
        int grow = rowOut + q*4 + r;
        float o = fmaxf(acc[ct][r] + bv, 0.f);
        OUT[(size_t)grow*DF + c] = o;
        ov[ct][r] = o;
      }
    }
    #pragma unroll
    for (int r=0; r<4; ++r){
      float p = 0.f;
      #pragma unroll
      for (int ct=0; ct<8; ++ct) p += ov[ct][r]*pwv[ct];
      p += __shfl_xor(p,8,16); p += __shfl_xor(p,4,16);
      p += __shfl_xor(p,2,16); p += __shfl_xor(p,1,16);
      if (c16 == 0) scores[rowOut + q*4 + r] = tanhf(p/nrm);
    }
  }
}

// ---------------- top-k via radix-select + pool + classifier ---------------
__global__ __launch_bounds__(1024) void k_topk(
    const float* __restrict__ scores, const float* __restrict__ H,
    const float* __restrict__ Wc1, const float* __restrict__ bc1,
    const float* __restrict__ Wc2, const float* __restrict__ bc2,
    float* __restrict__ out)
{
  __shared__ uint32_t keys[NNODE];            // 8KB monotone keys
  __shared__ uint32_t hist[64];
  __shared__ uint32_t wsum[16];               // block-scan wave sums
  __shared__ uint32_t sh_b, sh_rank, sh_cnt;
  __shared__ unsigned short selidx[KSEL+1];
  __shared__ float selval[KSEL+1];
  __shared__ float part[8*DF];
  __shared__ float emb[DF];
  __shared__ float hred[DF];

  const int t = threadIdx.x; const int b = blockIdx.x;
  const int lane = t & 63, wid = t >> 6;
  const float* sc = scores + b*NNODE;

  for (int i=t; i<NNODE; i+=1024) keys[i] = f2mono(sc[i]);
  __syncthreads();

  // ---- radix select: find threshold key T = 615th largest ----
  uint32_t prefix = 0, prefmask = 0, rank = KSEL, cntT = 0;
  #pragma unroll
  for (int lev=0; lev<6; ++lev){
    const int shift = (lev<5) ? (26 - 6*lev) : 0;
    const uint32_t bmask = (lev<5) ? 63u : 3u;
    if (t < 64) hist[t] = 0;
    __syncthreads();
    for (int i=t; i<NNODE; i+=1024){
      uint32_t k = keys[i];
      if ((k & prefmask) == prefix) atomicAdd(&hist[(k>>shift)&bmask], 1u);
    }
    __syncthreads();
    if (t < 64){
      uint32_t x = hist[t];
      #pragma unroll
      for (int off=1; off<64; off<<=1){        // inclusive suffix sum
        uint32_t y = __shfl_down(x, off, 64);
        if (t + off < 64) x += y;
      }
      uint32_t above = __shfl_down(x, 1, 64);
      if (t == 63) above = 0;
      if (above < rank && rank <= x){
        sh_b = (uint32_t)t; sh_rank = rank - above; sh_cnt = x - above;
      }
    }
    __syncthreads();
    prefix |= (sh_b << shift);
    prefmask |= (bmask << shift);
    rank = sh_rank; cntT = sh_cnt;
    __syncthreads();
  }
  const uint32_t T = prefix;
  const uint32_t m = rank;

  // ---- selection + compaction (block scans, shfl-based) ----
  uint32_t k0 = keys[2*t], k1 = keys[2*t+1];
  uint32_t eq0 = (k0 == T), eq1 = (k1 == T);
  uint32_t eqr0 = 0, eqr1 = 0;

  if (m != cntT){
    uint32_t v = eq0 + eq1, x = v;
    #pragma unroll
    for (int off=1; off<64; off<<=1){
      uint32_t y = __shfl_up(x, off, 64);
      if (lane >= off) x += y;
    }
    if (lane == 63) wsum[wid] = x;
    __syncthreads();
    if (wid == 0){
      uint32_t s = (lane < 16) ? wsum[lane] : 0;
      #pragma unroll
      for (int off=1; off<16; off<<=1){
        uint32_t y = __shfl_up(s, off, 64);
        if (lane >= off) s += y;
      }
      if (lane < 16) wsum[lane] = s;
    }
    __syncthreads();
    uint32_t excl = (wid ? wsum[wid-1] : 0) + x - v;
    eqr0 = excl; eqr1 = excl + eq0;
    __syncthreads();
  }

  uint32_t sel0 = (k0 > T) || (eq0 && eqr0 < m);
  uint32_t sel1 = (k1 > T) || (eq1 && eqr1 < m);
  {
    uint32_t v = sel0 + sel1, x = v;
    #pragma unroll
    for (int off=1; off<64; off<<=1){
      uint32_t y = __shfl_up(x, off, 64);
      if (lane >= off) x += y;
    }
    if (lane == 63) wsum[wid] = x;
    __syncthreads();
    if (wid == 0){
      uint32_t s = (lane < 16) ? wsum[lane] : 0;
      #pragma unroll
      for (int off=1; off<16; off<<=1){
        uint32_t y = __shfl_up(s, off, 64);
        if (lane >= off) s += y;
      }
      if (lane < 16) wsum[lane] = s;
    }
    __syncthreads();
    uint32_t excl = (wid ? wsum[wid-1] : 0) + x - v;
    if (sel0){ selidx[excl] = (unsigned short)(2*t);   selval[excl] = mono2f(k0); }
    if (sel1){ selidx[excl+sel0] = (unsigned short)(2*t+1); selval[excl+sel0] = mono2f(k1); }
  }
  __syncthreads();

  // ---- gated mean over the 615 selected rows (4-deep unrolled gather) ----
  const int pg = t >> 7, f = t & (DF-1);
  const float* Hb = H + (size_t)b*NNODE*DF;
  float accv = 0.f;
  int s2 = pg;
  for (; s2+24 < KSEL; s2 += 32){
    int i0=selidx[s2], i1=selidx[s2+8], i2=selidx[s2+16], i3=selidx[s2+24];
    float w0=selval[s2], w1=selval[s2+8], w2=selval[s2+16], w3=selval[s2+24];
    float v0=Hb[(size_t)i0*DF+f], v1=Hb[(size_t)i1*DF+f],
          v2=Hb[(size_t)i2*DF+f], v3=Hb[(size_t)i3*DF+f];
    accv += w0*v0 + w1*v1 + w2*v2 + w3*v3;
  }
  for (; s2<KSEL; s2+=8) accv += selval[s2]*Hb[(size_t)selidx[s2]*DF+f];
  part[pg*DF + f] = accv;
  __syncthreads();
  if (t < DF){
    float e = 0.f;
    for (int g2=0; g2<8; ++g2) e += part[g2*DF + t];
    emb[t] = e / (float)KSEL;
  }
  __syncthreads();
  if (t < DF){
    float hv = bc1[t];
    const float* wr = Wc1 + t*DF;
    for (int f2=0; f2<DF; ++f2) hv = fmaf(emb[f2], wr[f2], hv);
    hred[t] = fmaxf(hv, 0.f) * Wc2[t];
  }
  __syncthreads();
  if (t == 0){
    float o = bc2[0];
    for (int c2=0; c2<DF; ++c2) o += hred[c2];
    out[b] = o;
  }
}

// ---------------- launch ----------------
extern "C" void kernel_launch(void* const* d_in, const int* in_sizes, int n_in,
                              void* d_out, int out_size, void* d_ws, size_t ws_size,
                              hipStream_t stream)
{
  (void)in_sizes; (void)n_in; (void)out_size; (void)ws_size;
  const float* x   = (const float*)d_in[0];
  const int* esrc  = (const int*)d_in[1];
  const int* edst  = (const int*)d_in[2];
  const float* Wl1 = (const float*)d_in[3];
  const float* bl1 = (const float*)d_in[4];
  const float* Wr1 = (const float*)d_in[5];
  const float* Wl2 = (const float*)d_in[6];
  const float* bl2 = (const float*)d_in[7];
  const float* Wr2 = (const float*)d_in[8];
  const float* pw  = (const float*)d_in[9];
  const float* Wc1 = (const float*)d_in[10];
  const float* bc1 = (const float*)d_in[11];
  const float* Wc2 = (const float*)d_in[12];
  const float* bc2 = (const float*)d_in[13];
  float* out = (float*)d_out;

  char* ws = (char*)d_ws;                       // ~104 MB used
  float*    H1     = (float*)   (ws + 0);          // 32MB
  float*    H2     = (float*)   (ws + 33554432);   // 32MB
  float*    AGG    = (float*)   (ws + 67108864);   // 32MB
  uint32_t* deg    = (uint32_t*)(ws + 100663296);  // 256KB
  uint32_t* rowptr = (uint32_t*)(ws + 100925440);  // 65537 u32
  int*      col    = (int*)     (ws + 101187840);  // 2MB
  float*    scores = (float*)   (ws + 103284992);  // 256KB
  uint32_t* bsum   = (uint32_t*)(ws + 103547136);  // 256B
  unsigned short* Bpk = (unsigned short*)(ws + 103547392); // 256KB (2 layers)

  // allow 128KB dynamic LDS for k_aggX (idempotent; ignore errors)
  (void)hipFuncSetAttribute((const void*)k_aggX,
        hipFuncAttributeMaxDynamicSharedMemorySize, 131072);

  hipMemsetAsync(deg, 0, NT*sizeof(uint32_t), stream);

  // degree count (blocks 0..2047) + weight pack (blocks 2048..2079)
  k_deg    <<<ETOT/256 + 32, 256, 0, stream>>>(edst, deg, Wl1, Wr1, Wl2, Wr2, Bpk);
  k_scan1  <<<64, 1024, 0, stream>>>(deg, rowptr, bsum);
  k_scan2  <<<1, 64, 0, stream>>>(bsum);
  k_scan3  <<<64, 1024, 0, stream>>>(rowptr, bsum);
  k_scatter<<<ETOT/256, 256, 0, stream>>>(esrc, edst, rowptr, deg, col);

  // layer 1: slice-agg (LDS-staged) then MFMA combine
  k_aggX   <<<256, 512, 131072, stream>>>(x,  rowptr, col, AGG);
  k_comb<1><<<NT/64, 256, 0, stream>>>(AGG, x,  Bpk,         bl1, H1,
                                       nullptr, nullptr);
  // layer 2
  k_aggX   <<<256, 512, 131072, stream>>>(H1, rowptr, col, AGG);
  k_comb<2><<<NT/64, 256, 0, stream>>>(AGG, H1, Bpk + 65536, bl2, H2,
                                       pw, scores);

  k_topk<<<NB, 1024, 0, stream>>>(scores, H2, Wc1, bc1, Wc2, bc2, out);
}

// Round 13
// 256.820 us; speedup vs baseline: 1.1190x; 1.1190x over previous
//
#include <hip/hip_runtime.h>
#include <stdint.h>
#include <math.h>

// Problem constants (fixed by the reference)
#define NB    32          // graphs
#define NNODE 2048        // nodes per graph
#define EPB   16384       // edges per graph
#define NT    (NB*NNODE)  // 65536 total nodes
#define ETOT  (NB*EPB)    // 524288 edges
#define DF    128         // feature dim
#define KSEL  615         // ceil(0.3*2048)
#define SLICEW 8          // features per agg slice
#define XSTR  9           // LDS row stride in words (gcd(9,32)=1 -> all banks)

typedef __attribute__((ext_vector_type(8))) short bf16x8;
typedef __attribute__((ext_vector_type(4))) float f32x4;

// ---- split-precision helpers: f32 ~= hi(bf16) + lo(bf16), err ~2^-17 ----
__device__ __forceinline__ unsigned short f2bf(float f){
  uint32_t u = __float_as_uint(f);
  u += 0x7FFFu + ((u>>16)&1u);                 // RNE
  return (unsigned short)(u>>16);
}
__device__ __forceinline__ void split2(float f, unsigned short& hi, unsigned short& lo){
  unsigned short h = f2bf(f);
  float fh = __uint_as_float(((uint32_t)h)<<16);
  hi = h;
  lo = f2bf(f - fh);
}
// monotone u32 <-> f32 (ascending u32 == ascending float over all reals)
__device__ __forceinline__ uint32_t f2mono(float f){
  uint32_t u = __float_as_uint(f);
  return (u & 0x80000000u) ? ~u : (u | 0x80000000u);
}
__device__ __forceinline__ float mono2f(uint32_t m){
  uint32_t u = (m & 0x80000000u) ? (m ^ 0x80000000u) : ~m;
  return __uint_as_float(u);
}

// ---------------- CSR build ----------------
// blocks 0..2047: degree count (global atomics). blocks 2048..2079: packB.
__global__ void k_deg(const int* __restrict__ edst, uint32_t* __restrict__ deg,
                      const float* __restrict__ Wl1, const float* __restrict__ Wr1,
                      const float* __restrict__ Wl2, const float* __restrict__ Wr2,
                      unsigned short* __restrict__ Bpk){
  const int bid = blockIdx.x;
  if (bid < ETOT/256){
    int e = bid*256 + threadIdx.x;
    int g = e >> 14;                           // EPB = 2^14
    atomicAdd(&deg[g*NNODE + edst[e]], 1u);
  } else {
    // weight pack: Bpk elem offset ks*8192 + ct*1024 + part*512 + lane*8 + j
    int tt = (bid - ETOT/256)*256 + threadIdx.x;   // 0..8191
    int layer = tt >> 12;
    int t2 = tt & 4095;
    const float* Wl = layer ? Wl2 : Wl1;
    const float* Wr = layer ? Wr2 : Wr1;
    unsigned short* B = Bpk + (size_t)layer*65536;
    int lane = t2 & 63;
    int ct   = (t2>>6) & 7;
    int ks   = (t2>>9) & 7;
    int c  = ct*16 + (lane & 15);
    int k0 = ks*32 + ((lane>>4)<<3);
    size_t base = ((size_t)((ks*8+ct)*2)*64 + lane)*8;
    #pragma unroll
    for (int j=0;j<8;++j){
      int k = k0 + j;
      float v = (k < DF) ? Wl[c*DF + k] : Wr[c*DF + (k-DF)];
      unsigned short h, l; split2(v, h, l);
      B[base + j]       = h;
      B[base + 512 + j] = l;
    }
  }
}

// per-graph exclusive scan of degrees (graphs are independent: g*EPB base)
__global__ __launch_bounds__(256) void k_scanG(const uint32_t* __restrict__ deg,
                                               uint32_t* __restrict__ rowptr){
  __shared__ uint32_t wsum4[4];
  const int g = blockIdx.x, t = threadIdx.x;
  const int lane = t & 63, wid = t >> 6;
  const uint32_t* dg = deg + g*NNODE;
  uint32_t v[8]; const int b8 = t*8;
  uint32_t tsum = 0;
  #pragma unroll
  for (int j=0;j<8;++j){ v[j] = dg[b8+j]; tsum += v[j]; }
  uint32_t x = tsum;
  #pragma unroll
  for (int off=1; off<64; off<<=1){
    uint32_t y = __shfl_up(x, off, 64);
    if (lane >= off) x += y;
  }
  if (lane == 63) wsum4[wid] = x;
  __syncthreads();
  if (t == 0){
    uint32_t a = 0;
    #pragma unroll
    for (int w=0; w<4; ++w){ uint32_t tmp=wsum4[w]; wsum4[w]=a; a+=tmp; }
  }
  __syncthreads();
  uint32_t run = wsum4[wid] + x - tsum;        // thread-exclusive start
  uint32_t* rp = rowptr + g*NNODE + b8;
  #pragma unroll
  for (int j=0;j<8;++j){ rp[j] = g*EPB + run; run += v[j]; }
  if (g == 0 && t == 0) rowptr[NT] = ETOT;
}

__global__ void k_scatter(const int* __restrict__ esrc, const int* __restrict__ edst,
                          const uint32_t* __restrict__ rowptr, uint32_t* __restrict__ deg,
                          int* __restrict__ col){
  int e = blockIdx.x*256 + threadIdx.x;
  int g = e >> 14;
  int d = g*NNODE + edst[e];
  int s = g*NNODE + esrc[e];
  uint32_t old = atomicSub(&deg[d], 1u);
  col[rowptr[d] + old - 1u] = s;
}

// ---------------- aggregation via whole-graph LDS slice (v2) ---------------
// Block = (graph, 8-feature slice). Stage ALL 2048 rows' 32B slices into LDS
// with row stride 9 words (36B) -> row starts cover all 32 banks (gcd(9,32)=1,
// fixes r12's 2-phase 64B-row conflict storm). Stage col as u16 in LDS (walk
// never touches global for indices). Subgroup = 2 lanes x 8 dst rows; 2-deep
// pipelined b32 walk; flush aligned f32x4 to AGG. XCD swizzle: g = bid&31.
__global__ __launch_bounds__(512) void k_aggX(
    const float* __restrict__ Xin, const uint32_t* __restrict__ rowptr,
    const int* __restrict__ col, float* __restrict__ AGG)
{
  extern __shared__ uint32_t dynls[];
  float* Xs = (float*)dynls;                   // 2048*9 words = 72KB
  unsigned short* lc = (unsigned short*)(dynls + NNODE*XSTR);  // 32KB
  const int t = threadIdx.x;
  const int g = blockIdx.x & 31, sl = blockIdx.x >> 5;   // slice 0..15
  const int f0 = sl*SLICEW;
  const int gbase = g*NNODE;
  const uint32_t ebase = (uint32_t)g*EPB;

  // ---- stage col -> u16 ----
  {
    const int* cg = col + (size_t)g*EPB;
    for (int i=t; i<EPB; i+=512) lc[i] = (unsigned short)(cg[i] & (NNODE-1));
  }
  // ---- stage X slice (2 lanes per row, 4 floats each) ----
  {
    const int rr = t >> 1, qq = t & 1;
    #pragma unroll
    for (int p=0; p<8; ++p){
      int row = p*256 + rr;
      const float* src = Xin + (size_t)(gbase+row)*DF + f0 + qq*4;
      float4 vv = *(const float4*)src;
      float* d = Xs + row*XSTR + qq*4;
      d[0]=vv.x; d[1]=vv.y; d[2]=vv.z; d[3]=vv.w;
    }
  }
  __syncthreads();

  // ---- edge walk from LDS ----
  const int sg = t >> 1, q = t & 1;            // 256 subgroups x 8 rows
  int cur = sg*8;
  const int curEnd = cur + 8;
  const uint32_t kb = rowptr[gbase+cur] - ebase;
  const uint32_t ke = rowptr[gbase+curEnd] - ebase;
  uint32_t rstart = kb;
  uint32_t rnext  = rowptr[gbase+cur+1] - ebase;
  f32x4 accv = {0.f,0.f,0.f,0.f};

  auto flush = [&](){
    uint32_t d = rnext - rstart;
    float invd = 1.0f / (float)(d ? d : 1u);
    *(f32x4*)(AGG + (size_t)(gbase+cur)*DF + f0 + q*4) = accv * invd;
    accv = (f32x4){0.f,0.f,0.f,0.f};
    cur++;
    rstart = rnext;
    rnext = (cur < curEnd) ? rowptr[gbase+cur+1] - ebase : 0xFFFFFFFFu;
  };

  uint32_t e = kb;
  if (e < ke){
    int s = lc[e];
    const float* p0 = Xs + s*XSTR + q*4;
    f32x4 vcur = {p0[0], p0[1], p0[2], p0[3]};
    while (true){
      uint32_t e2 = e + 1;
      f32x4 vnext = {0.f,0.f,0.f,0.f};
      bool more = (e2 < ke);
      if (more){
        int s2 = lc[e2];
        const float* p1 = Xs + s2*XSTR + q*4;
        vnext = (f32x4){p1[0], p1[1], p1[2], p1[3]};   // issued before accv use
      }
      while (rnext <= e) flush();
      accv += vcur;
      if (!more) break;
      vcur = vnext; e = e2;
    }
  }
  while (cur < curEnd) flush();                // trailing (incl. empty) rows
}

// ---------------- SAGE combine: split-bf16 MFMA from AGG + X ---------------
// 256 threads, 4 independent waves x 16 rows (64 rows/block, no LDS).
template<int LAYER>
__global__ __launch_bounds__(256) void k_comb(
    const float* __restrict__ AGG, const float* __restrict__ Xin,
    const unsigned short* __restrict__ Bpk, const float* __restrict__ bias,
    float* __restrict__ OUT, const float* __restrict__ pw,
    float* __restrict__ scores)
{
  const int t = threadIdx.x;
  const int g = blockIdx.x & 31, jb = blockIdx.x >> 5;   // 32 blocks/graph
  const int l = t & 63, wid = t >> 6;
  const int q = l >> 4, c16 = l & 15;
  const int rowBase = g*NNODE + jb*64;
  const int arow = rowBase + wid*16 + c16;

  f32x4 aggv[8], own[8];
  #pragma unroll
  for (int ks4=0; ks4<4; ++ks4){
    const float* a = AGG + (size_t)arow*DF + ks4*32 + q*8;
    aggv[ks4*2]   = *(const f32x4*)a;
    aggv[ks4*2+1] = *(const f32x4*)(a+4);
    const float* s = Xin + (size_t)arow*DF + ks4*32 + q*8;
    own[ks4*2]    = *(const f32x4*)s;
    own[ks4*2+1]  = *(const f32x4*)(s+4);
  }

  f32x4 acc[8];
  #pragma unroll
  for (int ct=0; ct<8; ++ct) acc[ct] = (f32x4){0.f,0.f,0.f,0.f};

  #pragma unroll
  for (int ks=0; ks<8; ++ks){
    f32x4 A0 = (ks<4) ? aggv[ks*2]   : own[(ks-4)*2];
    f32x4 A1 = (ks<4) ? aggv[ks*2+1] : own[(ks-4)*2+1];
    float v[8] = {A0.x,A0.y,A0.z,A0.w,A1.x,A1.y,A1.z,A1.w};
    bf16x8 ahi, alo;
    #pragma unroll
    for (int j=0;j<8;++j){
      unsigned short h, lo_; split2(v[j], h, lo_);
      ahi[j] = (short)h; alo[j] = (short)lo_;
    }
    const unsigned short* bp = Bpk + (size_t)ks*8192 + l*8;
    #pragma unroll
    for (int ct=0; ct<8; ++ct){
      bf16x8 bhi = *(const bf16x8*)(bp + ct*1024);
      bf16x8 blo = *(const bf16x8*)(bp + ct*1024 + 512);
      acc[ct] = __builtin_amdgcn_mfma_f32_16x16x32_bf16(ahi, bhi, acc[ct], 0,0,0);
      acc[ct] = __builtin_amdgcn_mfma_f32_16x16x32_bf16(ahi, blo, acc[ct], 0,0,0);
      acc[ct] = __builtin_amdgcn_mfma_f32_16x16x32_bf16(alo, bhi, acc[ct], 0,0,0);
    }
  }

  const int rowOut = rowBase + wid*16;
  if constexpr (LAYER==1){
    #pragma unroll
    for (int ct=0; ct<8; ++ct){
      int c = ct*16 + c16;
      float bv = bias[c];
      #pragma unroll
      for (int r=0; r<4; ++r){
        int grow = rowOut + q*4 + r;
        OUT[(size_t)grow*DF + c] = fmaxf(acc[ct][r] + bv, 0.f);
      }
    }
  } else {
    float ov[8][4];
    float pwv[8];
    float n2 = 0.f;
    #pragma unroll
    for (int ct=0; ct<8; ++ct){ pwv[ct] = pw[ct*16 + c16]; n2 += pwv[ct]*pwv[ct]; }
    n2 += __shfl_xor(n2,8,16); n2 += __shfl_xor(n2,4,16);
    n2 += __shfl_xor(n2,2,16); n2 += __shfl_xor(n2,1,16);
    float nrm = sqrtf(n2);
    #pragma unroll
    for (int ct=0; ct<8; ++ct){
      int c = ct*16 + c16;
      float bv = bias[c];
      #pragma unroll
      for (int r=0; r<4; ++r){
        int grow = rowOut + q*4 + r;
        float o = fmaxf(acc[ct][r] + bv, 0.f);
        OUT[(size_t)grow*DF + c] = o;
        ov[ct][r] = o;
      }
    }
    #pragma unroll
    for (int r=0; r<4; ++r){
      float p = 0.f;
      #pragma unroll
      for (int ct=0; ct<8; ++ct) p += ov[ct][r]*pwv[ct];
      p += __shfl_xor(p,8,16); p += __shfl_xor(p,4,16);
      p += __shfl_xor(p,2,16); p += __shfl_xor(p,1,16);
      if (c16 == 0) scores[rowOut + q*4 + r] = tanhf(p/nrm);
    }
  }
}

// ---------------- top-k via radix-select + pool + classifier ---------------
__global__ __launch_bounds__(1024) void k_topk(
    const float* __restrict__ scores, const float* __restrict__ H,
    const float* __restrict__ Wc1, const float* __restrict__ bc1,
    const float* __restrict__ Wc2, const float* __restrict__ bc2,
    float* __restrict__ out)
{
  __shared__ uint32_t keys[NNODE];            // 8KB monotone keys
  __shared__ uint32_t hist[64];
  __shared__ uint32_t wsum[16];               // block-scan wave sums
  __shared__ uint32_t sh_b, sh_rank, sh_cnt;
  __shared__ unsigned short selidx[KSEL+1];
  __shared__ float selval[KSEL+1];
  __shared__ float part[8*DF];
  __shared__ float emb[DF];
  __shared__ float hred[DF];

  const int t = threadIdx.x; const int b = blockIdx.x;
  const int lane = t & 63, wid = t >> 6;
  const float* sc = scores + b*NNODE;

  for (int i=t; i<NNODE; i+=1024) keys[i] = f2mono(sc[i]);
  __syncthreads();

  // ---- radix select: find threshold key T = 615th largest ----
  uint32_t prefix = 0, prefmask = 0, rank = KSEL, cntT = 0;
  #pragma unroll
  for (int lev=0; lev<6; ++lev){
    const int shift = (lev<5) ? (26 - 6*lev) : 0;
    const uint32_t bmask = (lev<5) ? 63u : 3u;
    if (t < 64) hist[t] = 0;
    __syncthreads();
    for (int i=t; i<NNODE; i+=1024){
      uint32_t k = keys[i];
      if ((k & prefmask) == prefix) atomicAdd(&hist[(k>>shift)&bmask], 1u);
    }
    __syncthreads();
    if (t < 64){
      uint32_t x = hist[t];
      #pragma unroll
      for (int off=1; off<64; off<<=1){        // inclusive suffix sum
        uint32_t y = __shfl_down(x, off, 64);
        if (t + off < 64) x += y;
      }
      uint32_t above = __shfl_down(x, 1, 64);
      if (t == 63) above = 0;
      if (above < rank && rank <= x){
        sh_b = (uint32_t)t; sh_rank = rank - above; sh_cnt = x - above;
      }
    }
    __syncthreads();
    prefix |= (sh_b << shift);
    prefmask |= (bmask << shift);
    rank = sh_rank; cntT = sh_cnt;
    __syncthreads();
  }
  const uint32_t T = prefix;
  const uint32_t m = rank;

  // ---- selection + compaction (block scans, shfl-based) ----
  uint32_t k0 = keys[2*t], k1 = keys[2*t+1];
  uint32_t eq0 = (k0 == T), eq1 = (k1 == T);
  uint32_t eqr0 = 0, eqr1 = 0;

  if (m != cntT){
    uint32_t v = eq0 + eq1, x = v;
    #pragma unroll
    for (int off=1; off<64; off<<=1){
      uint32_t y = __shfl_up(x, off, 64);
      if (lane >= off) x += y;
    }
    if (lane == 63) wsum[wid] = x;
    __syncthreads();
    if (wid == 0){
      uint32_t s = (lane < 16) ? wsum[lane] : 0;
      #pragma unroll
      for (int off=1; off<16; off<<=1){
        uint32_t y = __shfl_up(s, off, 64);
        if (lane >= off) s += y;
      }
      if (lane < 16) wsum[lane] = s;
    }
    __syncthreads();
    uint32_t excl = (wid ? wsum[wid-1] : 0) + x - v;
    eqr0 = excl; eqr1 = excl + eq0;
    __syncthreads();
  }

  uint32_t sel0 = (k0 > T) || (eq0 && eqr0 < m);
  uint32_t sel1 = (k1 > T) || (eq1 && eqr1 < m);
  {
    uint32_t v = sel0 + sel1, x = v;
    #pragma unroll
    for (int off=1; off<64; off<<=1){
      uint32_t y = __shfl_up(x, off, 64);
      if (lane >= off) x += y;
    }
    if (lane == 63) wsum[wid] = x;
    __syncthreads();
    if (wid == 0){
      uint32_t s = (lane < 16) ? wsum[lane] : 0;
      #pragma unroll
      for (int off=1; off<16; off<<=1){
        uint32_t y = __shfl_up(s, off, 64);
        if (lane >= off) s += y;
      }
      if (lane < 16) wsum[lane] = s;
    }
    __syncthreads();
    uint32_t excl = (wid ? wsum[wid-1] : 0) + x - v;
    if (sel0){ selidx[excl] = (unsigned short)(2*t);   selval[excl] = mono2f(k0); }
    if (sel1){ selidx[excl+sel0] = (unsigned short)(2*t+1); selval[excl+sel0] = mono2f(k1); }
  }
  __syncthreads();

  // ---- gated mean over the 615 selected rows (4-deep unrolled gather) ----
  const int pg = t >> 7, f = t & (DF-1);
  const float* Hb = H + (size_t)b*NNODE*DF;
  float accv = 0.f;
  int s2 = pg;
  for (; s2+24 < KSEL; s2 += 32){
    int i0=selidx[s2], i1=selidx[s2+8], i2=selidx[s2+16], i3=selidx[s2+24];
    float w0=selval[s2], w1=selval[s2+8], w2=selval[s2+16], w3=selval[s2+24];
    float v0=Hb[(size_t)i0*DF+f], v1=Hb[(size_t)i1*DF+f],
          v2=Hb[(size_t)i2*DF+f], v3=Hb[(size_t)i3*DF+f];
    accv += w0*v0 + w1*v1 + w2*v2 + w3*v3;
  }
  for (; s2<KSEL; s2+=8) accv += selval[s2]*Hb[(size_t)selidx[s2]*DF+f];
  part[pg*DF + f] = accv;
  __syncthreads();
  if (t < DF){
    float e = 0.f;
    for (int g2=0; g2<8; ++g2) e += part[g2*DF + t];
    emb[t] = e / (float)KSEL;
  }
  __syncthreads();
  if (t < DF){
    float hv = bc1[t];
    const float* wr = Wc1 + t*DF;
    for (int f2=0; f2<DF; ++f2) hv = fmaf(emb[f2], wr[f2], hv);
    hred[t] = fmaxf(hv, 0.f) * Wc2[t];
  }
  __syncthreads();
  if (t == 0){
    float o = bc2[0];
    for (int c2=0; c2<DF; ++c2) o += hred[c2];
    out[b] = o;
  }
}

// ---------------- launch ----------------
extern "C" void kernel_launch(void* const* d_in, const int* in_sizes, int n_in,
                              void* d_out, int out_size, void* d_ws, size_t ws_size,
                              hipStream_t stream)
{
  (void)in_sizes; (void)n_in; (void)out_size; (void)ws_size;
  const float* x   = (const float*)d_in[0];
  const int* esrc  = (const int*)d_in[1];
  const int* edst  = (const int*)d_in[2];
  const float* Wl1 = (const float*)d_in[3];
  const float* bl1 = (const float*)d_in[4];
  const float* Wr1 = (const float*)d_in[5];
  const float* Wl2 = (const float*)d_in[6];
  const float* bl2 = (const float*)d_in[7];
  const float* Wr2 = (const float*)d_in[8];
  const float* pw  = (const float*)d_in[9];
  const float* Wc1 = (const float*)d_in[10];
  const float* bc1 = (const float*)d_in[11];
  const float* Wc2 = (const float*)d_in[12];
  const float* bc2 = (const float*)d_in[13];
  float* out = (float*)d_out;

  char* ws = (char*)d_ws;                       // ~104 MB used
  float*    H1     = (float*)   (ws + 0);          // 32MB
  float*    H2     = (float*)   (ws + 33554432);   // 32MB
  float*    AGG    = (float*)   (ws + 67108864);   // 32MB
  uint32_t* deg    = (uint32_t*)(ws + 100663296);  // 256KB
  uint32_t* rowptr = (uint32_t*)(ws + 100925440);  // 65537 u32
  int*      col    = (int*)     (ws + 101187840);  // 2MB
  float*    scores = (float*)   (ws + 103284992);  // 256KB
  unsigned short* Bpk = (unsigned short*)(ws + 103547392); // 256KB (2 layers)

  // allow 104KB dynamic LDS for k_aggX (host-side attr; graph-capture safe)
  (void)hipFuncSetAttribute((const void*)k_aggX,
        hipFuncAttributeMaxDynamicSharedMemorySize, 106496);

  hipMemsetAsync(deg, 0, NT*sizeof(uint32_t), stream);

  // degree count (blocks 0..2047) + weight pack (blocks 2048..2079)
  k_deg   <<<ETOT/256 + 32, 256, 0, stream>>>(edst, deg, Wl1, Wr1, Wl2, Wr2, Bpk);
  k_scanG <<<NB, 256, 0, stream>>>(deg, rowptr);
  k_scatter<<<ETOT/256, 256, 0, stream>>>(esrc, edst, rowptr, deg, col);

  // layer 1: slice-agg (LDS-staged, conflict-fixed) then MFMA combine
  k_aggX   <<<512, 512, 106496, stream>>>(x,  rowptr, col, AGG);
  k_comb<1><<<NT/64, 256, 0, stream>>>(AGG, x,  Bpk,         bl1, H1,
                                       nullptr, nullptr);
  // layer 2
  k_aggX   <<<512, 512, 106496, stream>>>(H1, rowptr, col, AGG);
  k_comb<2><<<NT/64, 256, 0, stream>>>(AGG, H1, Bpk + 65536, bl2, H2,
                                       pw, scores);

  k_topk<<<NB, 1024, 0, stream>>>(scores, H2, Wc1, bc1, Wc2, bc2, out);
}

// Round 14
// 208.415 us; speedup vs baseline: 1.3789x; 1.2323x over previous
//
#include <hip/hip_runtime.h>
#include <stdint.h>
#include <math.h>

// Problem constants (fixed by the reference)
#define NB    32          // graphs
#define NNODE 2048        // nodes per graph
#define EPB   16384       // edges per graph
#define NT    (NB*NNODE)  // 65536 total nodes
#define ETOT  (NB*EPB)    // 524288 edges
#define DF    128         // feature dim
#define KSEL  615         // ceil(0.3*2048)
#define SLICEW 8          // features per agg slice
#define XSTR  9           // LDS row stride in words (gcd(9,32)=1 -> all banks)

typedef __attribute__((ext_vector_type(8))) short bf16x8;
typedef __attribute__((ext_vector_type(4))) float f32x4;

// ---- split-precision helpers: f32 ~= hi(bf16) + lo(bf16), err ~2^-17 ----
__device__ __forceinline__ unsigned short f2bf(float f){
  uint32_t u = __float_as_uint(f);
  u += 0x7FFFu + ((u>>16)&1u);                 // RNE
  return (unsigned short)(u>>16);
}
__device__ __forceinline__ void split2(float f, unsigned short& hi, unsigned short& lo){
  unsigned short h = f2bf(f);
  float fh = __uint_as_float(((uint32_t)h)<<16);
  hi = h;
  lo = f2bf(f - fh);
}
// monotone u32 <-> f32 (ascending u32 == ascending float over all reals)
__device__ __forceinline__ uint32_t f2mono(float f){
  uint32_t u = __float_as_uint(f);
  return (u & 0x80000000u) ? ~u : (u | 0x80000000u);
}
__device__ __forceinline__ float mono2f(uint32_t m){
  uint32_t u = (m & 0x80000000u) ? (m ^ 0x80000000u) : ~m;
  return __uint_as_float(u);
}

// ---------------- CSR build ----------------
// blocks 0..2047: degree count (global atomics). blocks 2048..2079: packB.
__global__ void k_deg(const int* __restrict__ edst, uint32_t* __restrict__ deg,
                      const float* __restrict__ Wl1, const float* __restrict__ Wr1,
                      const float* __restrict__ Wl2, const float* __restrict__ Wr2,
                      unsigned short* __restrict__ Bpk){
  const int bid = blockIdx.x;
  if (bid < ETOT/256){
    int e = bid*256 + threadIdx.x;
    int g = e >> 14;                           // EPB = 2^14
    atomicAdd(&deg[g*NNODE + edst[e]], 1u);
  } else {
    // weight pack: Bpk elem offset ks*8192 + ct*1024 + part*512 + lane*8 + j
    int tt = (bid - ETOT/256)*256 + threadIdx.x;   // 0..8191
    int layer = tt >> 12;
    int t2 = tt & 4095;
    const float* Wl = layer ? Wl2 : Wl1;
    const float* Wr = layer ? Wr2 : Wr1;
    unsigned short* B = Bpk + (size_t)layer*65536;
    int lane = t2 & 63;
    int ct   = (t2>>6) & 7;
    int ks   = (t2>>9) & 7;
    int c  = ct*16 + (lane & 15);
    int k0 = ks*32 + ((lane>>4)<<3);
    size_t base = ((size_t)((ks*8+ct)*2)*64 + lane)*8;
    #pragma unroll
    for (int j=0;j<8;++j){
      int k = k0 + j;
      float v = (k < DF) ? Wl[c*DF + k] : Wr[c*DF + (k-DF)];
      unsigned short h, l; split2(v, h, l);
      B[base + j]       = h;
      B[base + 512 + j] = l;
    }
  }
}

// per-graph exclusive scan of degrees (graphs are independent: g*EPB base)
__global__ __launch_bounds__(256) void k_scanG(const uint32_t* __restrict__ deg,
                                               uint32_t* __restrict__ rowptr){
  __shared__ uint32_t wsum4[4];
  const int g = blockIdx.x, t = threadIdx.x;
  const int lane = t & 63, wid = t >> 6;
  const uint32_t* dg = deg + g*NNODE;
  uint32_t v[8]; const int b8 = t*8;
  uint32_t tsum = 0;
  #pragma unroll
  for (int j=0;j<8;++j){ v[j] = dg[b8+j]; tsum += v[j]; }
  uint32_t x = tsum;
  #pragma unroll
  for (int off=1; off<64; off<<=1){
    uint32_t y = __shfl_up(x, off, 64);
    if (lane >= off) x += y;
  }
  if (lane == 63) wsum4[wid] = x;
  __syncthreads();
  if (t == 0){
    uint32_t a = 0;
    #pragma unroll
    for (int w=0; w<4; ++w){ uint32_t tmp=wsum4[w]; wsum4[w]=a; a+=tmp; }
  }
  __syncthreads();
  uint32_t run = wsum4[wid] + x - tsum;        // thread-exclusive start
  uint32_t* rp = rowptr + g*NNODE + b8;
  #pragma unroll
  for (int j=0;j<8;++j){ rp[j] = g*EPB + run; run += v[j]; }
  if (g == 0 && t == 0) rowptr[NT] = ETOT;
}

// scatter edges into CSR order; col stored as u16 LOCAL node id
__global__ void k_scatter(const int* __restrict__ esrc, const int* __restrict__ edst,
                          const uint32_t* __restrict__ rowptr, uint32_t* __restrict__ deg,
                          unsigned short* __restrict__ colh){
  int e = blockIdx.x*256 + threadIdx.x;
  int g = e >> 14;
  int d = g*NNODE + edst[e];
  uint32_t old = atomicSub(&deg[d], 1u);
  colh[rowptr[d] + old - 1u] = (unsigned short)esrc[e];
}

// ---------------- aggregation via whole-graph LDS slice (v3) ---------------
// Block = (graph, 8-feature slice), 1024 threads (16 waves). Stage ALL 2048
// rows' 32B slices (stride 9 words -> all 32 banks), col (u16, 32KB) AND
// rowptr (8KB) into LDS -> the edge walk touches NO global memory except the
// final AGG stores. Subgroup = 2 lanes x 4 dst rows (512 subgroups, ~32
// edges each); 2-deep pipelined b32 walk; flush f32x4 to AGG on row change.
// XCD swizzle: g = bid&31.
__global__ __launch_bounds__(1024, 1) void k_aggX(
    const float* __restrict__ Xin, const uint32_t* __restrict__ rowptr,
    const unsigned short* __restrict__ colh, float* __restrict__ AGG)
{
  extern __shared__ uint32_t dynls[];
  float* Xs = (float*)dynls;                             // 2048*9 w = 72KB
  unsigned short* lc = (unsigned short*)(dynls + NNODE*XSTR);  // 32KB
  uint32_t* lrp = dynls + NNODE*XSTR + EPB/2;            // 2049 u32 = 8.2KB
  const int t = threadIdx.x;
  const int g = blockIdx.x & 31, sl = blockIdx.x >> 5;   // slice 0..15
  const int f0 = sl*SLICEW;
  const int gbase = g*NNODE;
  const uint32_t ebase = (uint32_t)g*EPB;

  // ---- stage col (u16, vectorized as u32) ----
  {
    const uint32_t* cg = (const uint32_t*)(colh + (size_t)g*EPB);
    uint32_t* lc32 = (uint32_t*)lc;
    #pragma unroll
    for (int p=0; p<8; ++p) lc32[p*1024 + t] = cg[p*1024 + t];
  }
  // ---- stage rowptr (tile-relative) ----
  for (int i=t; i<NNODE+1; i+=1024) lrp[i] = rowptr[gbase+i] - ebase;
  // ---- stage X slice (2 lanes per row, 4 floats each) ----
  {
    const int rr = t >> 1, qq = t & 1;
    #pragma unroll
    for (int p=0; p<4; ++p){
      int row = p*512 + rr;
      const float* src = Xin + (size_t)(gbase+row)*DF + f0 + qq*4;
      float4 vv = *(const float4*)src;
      float* d = Xs + row*XSTR + qq*4;
      d[0]=vv.x; d[1]=vv.y; d[2]=vv.z; d[3]=vv.w;
    }
  }
  __syncthreads();

  // ---- edge walk, all-LDS ----
  const int sg = t >> 1, q = t & 1;            // 512 subgroups x 4 rows
  int cur = sg*4;
  const int curEnd = cur + 4;
  const uint32_t kb = lrp[cur];
  const uint32_t ke = lrp[curEnd];
  uint32_t rstart = kb;
  uint32_t rnext  = lrp[cur+1];
  f32x4 accv = {0.f,0.f,0.f,0.f};

  auto flush = [&](){
    uint32_t d = rnext - rstart;
    float invd = 1.0f / (float)(d ? d : 1u);
    *(f32x4*)(AGG + (size_t)(gbase+cur)*DF + f0 + q*4) = accv * invd;
    accv = (f32x4){0.f,0.f,0.f,0.f};
    cur++;
    rstart = rnext;
    rnext = (cur < curEnd) ? lrp[cur+1] : 0xFFFFFFFFu;
  };

  uint32_t e = kb;
  if (e < ke){
    int s = lc[e];
    const float* p0 = Xs + s*XSTR + q*4;
    f32x4 vcur = {p0[0], p0[1], p0[2], p0[3]};
    while (true){
      uint32_t e2 = e + 1;
      f32x4 vnext = {0.f,0.f,0.f,0.f};
      bool more = (e2 < ke);
      if (more){
        int s2 = lc[e2];
        const float* p1 = Xs + s2*XSTR + q*4;
        vnext = (f32x4){p1[0], p1[1], p1[2], p1[3]};   // issued before accv use
      }
      while (rnext <= e) flush();
      accv += vcur;
      if (!more) break;
      vcur = vnext; e = e2;
    }
  }
  while (cur < curEnd) flush();                // trailing (incl. empty) rows
}

// ---------------- SAGE combine: split-bf16 MFMA from AGG + X ---------------
// 256 threads, 4 independent waves x 16 rows (64 rows/block, no LDS).
template<int LAYER>
__global__ __launch_bounds__(256) void k_comb(
    const float* __restrict__ AGG, const float* __restrict__ Xin,
    const unsigned short* __restrict__ Bpk, const float* __restrict__ bias,
    float* __restrict__ OUT, const float* __restrict__ pw,
    float* __restrict__ scores)
{
  const int t = threadIdx.x;
  const int g = blockIdx.x & 31, jb = blockIdx.x >> 5;   // 32 blocks/graph
  const int l = t & 63, wid = t >> 6;
  const int q = l >> 4, c16 = l & 15;
  const int rowBase = g*NNODE + jb*64;
  const int arow = rowBase + wid*16 + c16;

  f32x4 aggv[8], own[8];
  #pragma unroll
  for (int ks4=0; ks4<4; ++ks4){
    const float* a = AGG + (size_t)arow*DF + ks4*32 + q*8;
    aggv[ks4*2]   = *(const f32x4*)a;
    aggv[ks4*2+1] = *(const f32x4*)(a+4);
    const float* s = Xin + (size_t)arow*DF + ks4*32 + q*8;
    own[ks4*2]    = *(const f32x4*)s;
    own[ks4*2+1]  = *(const f32x4*)(s+4);
  }

  f32x4 acc[8];
  #pragma unroll
  for (int ct=0; ct<8; ++ct) acc[ct] = (f32x4){0.f,0.f,0.f,0.f};

  #pragma unroll
  for (int ks=0; ks<8; ++ks){
    f32x4 A0 = (ks<4) ? aggv[ks*2]   : own[(ks-4)*2];
    f32x4 A1 = (ks<4) ? aggv[ks*2+1] : own[(ks-4)*2+1];
    float v[8] = {A0.x,A0.y,A0.z,A0.w,A1.x,A1.y,A1.z,A1.w};
    bf16x8 ahi, alo;
    #pragma unroll
    for (int j=0;j<8;++j){
      unsigned short h, lo_; split2(v[j], h, lo_);
      ahi[j] = (short)h; alo[j] = (short)lo_;
    }
    const unsigned short* bp = Bpk + (size_t)ks*8192 + l*8;
    #pragma unroll
    for (int ct=0; ct<8; ++ct){
      bf16x8 bhi = *(const bf16x8*)(bp + ct*1024);
      bf16x8 blo = *(const bf16x8*)(bp + ct*1024 + 512);
      acc[ct] = __builtin_amdgcn_mfma_f32_16x16x32_bf16(ahi, bhi, acc[ct], 0,0,0);
      acc[ct] = __builtin_amdgcn_mfma_f32_16x16x32_bf16(ahi, blo, acc[ct], 0,0,0);
      acc[ct] = __builtin_amdgcn_mfma_f32_16x16x32_bf16(alo, bhi, acc[ct], 0,0,0);
    }
  }

  const int rowOut = rowBase + wid*16;
  if constexpr (LAYER==1){
    #pragma unroll
    for (int ct=0; ct<8; ++ct){
      int c = ct*16 + c16;
      float bv = bias[c];
      #pragma unroll
      for (int r=0; r<4; ++r){
        int grow = rowOut + q*4 + r;
        OUT[(size_t)grow*DF + c] = fmaxf(acc[ct][r] + bv, 0.f);
      }
    }
  } else {
    float ov[8][4];
    float pwv[8];
    float n2 = 0.f;
    #pragma unroll
    for (int ct=0; ct<8; ++ct){ pwv[ct] = pw[ct*16 + c16]; n2 += pwv[ct]*pwv[ct]; }
    n2 += __shfl_xor(n2,8,16); n2 += __shfl_xor(n2,4,16);
    n2 += __shfl_xor(n2,2,16); n2 += __shfl_xor(n2,1,16);
    float nrm = sqrtf(n2);
    #pragma unroll
    for (int ct=0; ct<8; ++ct){
      int c = ct*16 + c16;
      float bv = bias[c];
      #pragma unroll
      for (int r=0; r<4; ++r){
        int grow = rowOut + q*4 + r;
        float o = fmaxf(acc[ct][r] + bv, 0.f);
        OUT[(size_t)grow*DF + c] = o;
        ov[ct][r] = o;
      }
    }
    #pragma unroll
    for (int r=0; r<4; ++r){
      float p = 0.f;
      #pragma unroll
      for (int ct=0; ct<8; ++ct) p += ov[ct][r]*pwv[ct];
      p += __shfl_xor(p,8,16); p += __shfl_xor(p,4,16);
      p += __shfl_xor(p,2,16); p += __shfl_xor(p,1,16);
      if (c16 == 0) scores[rowOut + q*4 + r] = tanhf(p/nrm);
    }
  }
}

// ---------------- top-k via radix-select + pool + classifier ---------------
__global__ __launch_bounds__(1024) void k_topk(
    const float* __restrict__ scores, const float* __restrict__ H,
    const float* __restrict__ Wc1, const float* __restrict__ bc1,
    const float* __restrict__ Wc2, const float* __restrict__ bc2,
    float* __restrict__ out)
{
  __shared__ uint32_t keys[NNODE];            // 8KB monotone keys
  __shared__ uint32_t hist[64];
  __shared__ uint32_t wsum[16];               // block-scan wave sums
  __shared__ uint32_t sh_b, sh_rank, sh_cnt;
  __shared__ unsigned short selidx[KSEL+1];
  __shared__ float selval[KSEL+1];
  __shared__ float part[8*DF];
  __shared__ float emb[DF];
  __shared__ float hred[DF];

  const int t = threadIdx.x; const int b = blockIdx.x;
  const int lane = t & 63, wid = t >> 6;
  const float* sc = scores + b*NNODE;

  for (int i=t; i<NNODE; i+=1024) keys[i] = f2mono(sc[i]);
  __syncthreads();

  // ---- radix select: find threshold key T = 615th largest ----
  uint32_t prefix = 0, prefmask = 0, rank = KSEL, cntT = 0;
  #pragma unroll
  for (int lev=0; lev<6; ++lev){
    const int shift = (lev<5) ? (26 - 6*lev) : 0;
    const uint32_t bmask = (lev<5) ? 63u : 3u;
    if (t < 64) hist[t] = 0;
    __syncthreads();
    for (int i=t; i<NNODE; i+=1024){
      uint32_t k = keys[i];
      if ((k & prefmask) == prefix) atomicAdd(&hist[(k>>shift)&bmask], 1u);
    }
    __syncthreads();
    if (t < 64){
      uint32_t x = hist[t];
      #pragma unroll
      for (int off=1; off<64; off<<=1){        // inclusive suffix sum
        uint32_t y = __shfl_down(x, off, 64);
        if (t + off < 64) x += y;
      }
      uint32_t above = __shfl_down(x, 1, 64);
      if (t == 63) above = 0;
      if (above < rank && rank <= x){
        sh_b = (uint32_t)t; sh_rank = rank - above; sh_cnt = x - above;
      }
    }
    __syncthreads();
    prefix |= (sh_b << shift);
    prefmask |= (bmask << shift);
    rank = sh_rank; cntT = sh_cnt;
    __syncthreads();
  }
  const uint32_t T = prefix;
  const uint32_t m = rank;

  // ---- selection + compaction (block scans, shfl-based) ----
  uint32_t k0 = keys[2*t], k1 = keys[2*t+1];
  uint32_t eq0 = (k0 == T), eq1 = (k1 == T);
  uint32_t eqr0 = 0, eqr1 = 0;

  if (m != cntT){
    uint32_t v = eq0 + eq1, x = v;
    #pragma unroll
    for (int off=1; off<64; off<<=1){
      uint32_t y = __shfl_up(x, off, 64);
      if (lane >= off) x += y;
    }
    if (lane == 63) wsum[wid] = x;
    __syncthreads();
    if (wid == 0){
      uint32_t s = (lane < 16) ? wsum[lane] : 0;
      #pragma unroll
      for (int off=1; off<16; off<<=1){
        uint32_t y = __shfl_up(s, off, 64);
        if (lane >= off) s += y;
      }
      if (lane < 16) wsum[lane] = s;
    }
    __syncthreads();
    uint32_t excl = (wid ? wsum[wid-1] : 0) + x - v;
    eqr0 = excl; eqr1 = excl + eq0;
    __syncthreads();
  }

  uint32_t sel0 = (k0 > T) || (eq0 && eqr0 < m);
  uint32_t sel1 = (k1 > T) || (eq1 && eqr1 < m);
  {
    uint32_t v = sel0 + sel1, x = v;
    #pragma unroll
    for (int off=1; off<64; off<<=1){
      uint32_t y = __shfl_up(x, off, 64);
      if (lane >= off) x += y;
    }
    if (lane == 63) wsum[wid] = x;
    __syncthreads();
    if (wid == 0){
      uint32_t s = (lane < 16) ? wsum[lane] : 0;
      #pragma unroll
      for (int off=1; off<16; off<<=1){
        uint32_t y = __shfl_up(s, off, 64);
        if (lane >= off) s += y;
      }
      if (lane < 16) wsum[lane] = s;
    }
    __syncthreads();
    uint32_t excl = (wid ? wsum[wid-1] : 0) + x - v;
    if (sel0){ selidx[excl] = (unsigned short)(2*t);   selval[excl] = mono2f(k0); }
    if (sel1){ selidx[excl+sel0] = (unsigned short)(2*t+1); selval[excl+sel0] = mono2f(k1); }
  }
  __syncthreads();

  // ---- gated mean over the 615 selected rows (4-deep unrolled gather) ----
  const int pg = t >> 7, f = t & (DF-1);
  const float* Hb = H + (size_t)b*NNODE*DF;
  float accv = 0.f;
  int s2 = pg;
  for (; s2+24 < KSEL; s2 += 32){
    int i0=selidx[s2], i1=selidx[s2+8], i2=selidx[s2+16], i3=selidx[s2+24];
    float w0=selval[s2], w1=selval[s2+8], w2=selval[s2+16], w3=selval[s2+24];
    float v0=Hb[(size_t)i0*DF+f], v1=Hb[(size_t)i1*DF+f],
          v2=Hb[(size_t)i2*DF+f], v3=Hb[(size_t)i3*DF+f];
    accv += w0*v0 + w1*v1 + w2*v2 + w3*v3;
  }
  for (; s2<KSEL; s2+=8) accv += selval[s2]*Hb[(size_t)selidx[s2]*DF+f];
  part[pg*DF + f] = accv;
  __syncthreads();
  if (t < DF){
    float e = 0.f;
    for (int g2=0; g2<8; ++g2) e += part[g2*DF + t];
    emb[t] = e / (float)KSEL;
  }
  __syncthreads();
  if (t < DF){
    float hv = bc1[t];
    const float* wr = Wc1 + t*DF;
    for (int f2=0; f2<DF; ++f2) hv = fmaf(emb[f2], wr[f2], hv);
    hred[t] = fmaxf(hv, 0.f) * Wc2[t];
  }
  __syncthreads();
  if (t == 0){
    float o = bc2[0];
    for (int c2=0; c2<DF; ++c2) o += hred[c2];
    out[b] = o;
  }
}

// ---------------- launch ----------------
extern "C" void kernel_launch(void* const* d_in, const int* in_sizes, int n_in,
                              void* d_out, int out_size, void* d_ws, size_t ws_size,
                              hipStream_t stream)
{
  (void)in_sizes; (void)n_in; (void)out_size; (void)ws_size;
  const float* x   = (const float*)d_in[0];
  const int* esrc  = (const int*)d_in[1];
  const int* edst  = (const int*)d_in[2];
  const float* Wl1 = (const float*)d_in[3];
  const float* bl1 = (const float*)d_in[4];
  const float* Wr1 = (const float*)d_in[5];
  const float* Wl2 = (const float*)d_in[6];
  const float* bl2 = (const float*)d_in[7];
  const float* Wr2 = (const float*)d_in[8];
  const float* pw  = (const float*)d_in[9];
  const float* Wc1 = (const float*)d_in[10];
  const float* bc1 = (const float*)d_in[11];
  const float* Wc2 = (const float*)d_in[12];
  const float* bc2 = (const float*)d_in[13];
  float* out = (float*)d_out;

  char* ws = (char*)d_ws;                       // ~103 MB used
  float*    H1     = (float*)   (ws + 0);          // 32MB
  float*    H2     = (float*)   (ws + 33554432);   // 32MB
  float*    AGG    = (float*)   (ws + 67108864);   // 32MB
  uint32_t* deg    = (uint32_t*)(ws + 100663296);  // 256KB
  uint32_t* rowptr = (uint32_t*)(ws + 100925440);  // 65537 u32
  unsigned short* colh = (unsigned short*)(ws + 101187840); // 1MB u16
  float*    scores = (float*)   (ws + 102236160);  // 256KB
  unsigned short* Bpk = (unsigned short*)(ws + 102498560); // 256KB (2 layers)

  // allow 112.2KB dynamic LDS for k_aggX (host-side attr; graph-capture safe)
  (void)hipFuncSetAttribute((const void*)k_aggX,
        hipFuncAttributeMaxDynamicSharedMemorySize, 114948);

  hipMemsetAsync(deg, 0, NT*sizeof(uint32_t), stream);

  // degree count (blocks 0..2047) + weight pack (blocks 2048..2079)
  k_deg   <<<ETOT/256 + 32, 256, 0, stream>>>(edst, deg, Wl1, Wr1, Wl2, Wr2, Bpk);
  k_scanG <<<NB, 256, 0, stream>>>(deg, rowptr);
  k_scatter<<<ETOT/256, 256, 0, stream>>>(esrc, edst, rowptr, deg, colh);

  // layer 1: slice-agg (all-LDS walk) then MFMA combine
  k_aggX   <<<512, 1024, 114948, stream>>>(x,  rowptr, colh, AGG);
  k_comb<1><<<NT/64, 256, 0, stream>>>(AGG, x,  Bpk,         bl1, H1,
                                       nullptr, nullptr);
  // layer 2
  k_aggX   <<<512, 1024, 114948, stream>>>(H1, rowptr, colh, AGG);
  k_comb<2><<<NT/64, 256, 0, stream>>>(AGG, H1, Bpk + 65536, bl2, H2,
                                       pw, scores);

  k_topk<<<NB, 1024, 0, stream>>>(scores, H2, Wc1, bc1, Wc2, bc2, out);
}

// Round 15
// 153.116 us; speedup vs baseline: 1.8769x; 1.3612x over previous
//
#include <hip/hip_runtime.h>
#include <stdint.h>
#include <math.h>

// Problem constants (fixed by the reference)
#define NB    32          // graphs
#define NNODE 2048        // nodes per graph
#define EPB   16384       // edges per graph
#define NT    (NB*NNODE)  // 65536 total nodes
#define ETOT  (NB*EPB)    // 524288 edges
#define DF    128         // feature dim
#define KSEL  615         // ceil(0.3*2048)
#define EMAX  512         // LDS-staged edge cap per 32-row tile (mean 256)

typedef __attribute__((ext_vector_type(8))) short bf16x8;
typedef __attribute__((ext_vector_type(4))) float f32x4;

// ---- split-precision helpers: f32 ~= hi(bf16) + lo(bf16), err ~2^-17 ----
__device__ __forceinline__ unsigned short f2bf(float f){
  uint32_t u = __float_as_uint(f);
  u += 0x7FFFu + ((u>>16)&1u);                 // RNE
  return (unsigned short)(u>>16);
}
__device__ __forceinline__ void split2(float f, unsigned short& hi, unsigned short& lo){
  unsigned short h = f2bf(f);
  float fh = __uint_as_float(((uint32_t)h)<<16);
  hi = h;
  lo = f2bf(f - fh);
}
// monotone u32 <-> f32 (ascending u32 == ascending float over all reals)
__device__ __forceinline__ uint32_t f2mono(float f){
  uint32_t u = __float_as_uint(f);
  return (u & 0x80000000u) ? ~u : (u | 0x80000000u);
}
__device__ __forceinline__ float mono2f(uint32_t m){
  uint32_t u = (m & 0x80000000u) ? (m ^ 0x80000000u) : ~m;
  return __uint_as_float(u);
}

// ---------------- CSR build ----------------
// blocks 0..2047: degree count (global atomics). blocks 2048..2079: packB.
__global__ void k_deg(const int* __restrict__ edst, uint32_t* __restrict__ deg,
                      const float* __restrict__ Wl1, const float* __restrict__ Wr1,
                      const float* __restrict__ Wl2, const float* __restrict__ Wr2,
                      unsigned short* __restrict__ Bpk){
  const int bid = blockIdx.x;
  if (bid < ETOT/256){
    int e = bid*256 + threadIdx.x;
    int g = e >> 14;                           // EPB = 2^14
    atomicAdd(&deg[g*NNODE + edst[e]], 1u);
  } else {
    // weight pack: Bpk elem offset ks*8192 + ct*1024 + part*512 + lane*8 + j
    int tt = (bid - ETOT/256)*256 + threadIdx.x;   // 0..8191
    int layer = tt >> 12;
    int t2 = tt & 4095;
    const float* Wl = layer ? Wl2 : Wl1;
    const float* Wr = layer ? Wr2 : Wr1;
    unsigned short* B = Bpk + (size_t)layer*65536;
    int lane = t2 & 63;
    int ct   = (t2>>6) & 7;
    int ks   = (t2>>9) & 7;
    int c  = ct*16 + (lane & 15);
    int k0 = ks*32 + ((lane>>4)<<3);
    size_t base = ((size_t)((ks*8+ct)*2)*64 + lane)*8;
    #pragma unroll
    for (int j=0;j<8;++j){
      int k = k0 + j;
      float v = (k < DF) ? Wl[c*DF + k] : Wr[c*DF + (k-DF)];
      unsigned short h, l; split2(v, h, l);
      B[base + j]       = h;
      B[base + 512 + j] = l;
    }
  }
}

// per-graph exclusive scan of degrees (graphs independent: g*EPB base)
__global__ __launch_bounds__(256) void k_scanG(const uint32_t* __restrict__ deg,
                                               uint32_t* __restrict__ rowptr){
  __shared__ uint32_t wsum4[4];
  const int g = blockIdx.x, t = threadIdx.x;
  const int lane = t & 63, wid = t >> 6;
  const uint32_t* dg = deg + g*NNODE;
  uint32_t v[8]; const int b8 = t*8;
  uint32_t tsum = 0;
  #pragma unroll
  for (int j=0;j<8;++j){ v[j] = dg[b8+j]; tsum += v[j]; }
  uint32_t x = tsum;
  #pragma unroll
  for (int off=1; off<64; off<<=1){
    uint32_t y = __shfl_up(x, off, 64);
    if (lane >= off) x += y;
  }
  if (lane == 63) wsum4[wid] = x;
  __syncthreads();
  if (t == 0){
    uint32_t a = 0;
    #pragma unroll
    for (int w=0; w<4; ++w){ uint32_t tmp=wsum4[w]; wsum4[w]=a; a+=tmp; }
  }
  __syncthreads();
  uint32_t run = wsum4[wid] + x - tsum;        // thread-exclusive start
  uint32_t* rp = rowptr + g*NNODE + b8;
  #pragma unroll
  for (int j=0;j<8;++j){ rp[j] = g*EPB + run; run += v[j]; }
  if (g == 0 && t == 0) rowptr[NT] = ETOT;
}

// scatter edges into CSR order; col stored as u16 LOCAL node id
__global__ void k_scatter(const int* __restrict__ esrc, const int* __restrict__ edst,
                          const uint32_t* __restrict__ rowptr, uint32_t* __restrict__ deg,
                          unsigned short* __restrict__ colh){
  int e = blockIdx.x*256 + threadIdx.x;
  int g = e >> 14;
  int d = g*NNODE + edst[e];
  uint32_t old = atomicSub(&deg[d], 1u);
  colh[rowptr[d] + old - 1u] = (unsigned short)esrc[e];
}

// ---------------- fused SAGE layer: pipelined gather + split-bf16 MFMA -----
// 128 threads, 32 rows/block (r11's proven 49us structure). Phase 0: stage
// CSR slice (u16 col) to LDS. Phase 1: streaming gather — each 32-lane group
// owns a contiguous 8-row CSR segment, register double-buffer (16 loads in
// flight), flush to LDS on row change. Phase 2: 2 waves x 16 rows, K=256
// (ks0-3 agg from LDS, ks4-7 own row), 3 MFMAs per (ct,ks).
// XCD swizzle: graph = bid&31.
template<int LAYER>
__global__ __launch_bounds__(128, 4) void k_sage(
    const float* __restrict__ Xin, const uint32_t* __restrict__ rowptr,
    const unsigned short* __restrict__ colh, const unsigned short* __restrict__ Bpk,
    const float* __restrict__ bias, float* __restrict__ OUT,
    const float* __restrict__ pw, float* __restrict__ scores)
{
  __shared__ float smemA[32][132];             // 16.9KB, +4 float pad per row
  __shared__ unsigned short lcol[EMAX];        // 1KB staged local edge ids
  __shared__ uint32_t lrpl[33];                // tile-relative rowptr

  const int t = threadIdx.x;
  const int g = blockIdx.x & 31, jb = blockIdx.x >> 5;   // 64 blocks/graph
  const int rowBase = g*NNODE + jb*32;
  const float* Xg = Xin + (size_t)(g*NNODE)*DF;          // graph-local rows

  // ---- phase 0: stage CSR slice ----
  const uint32_t e0 = rowptr[rowBase];
  if (t < 33) lrpl[t] = rowptr[rowBase + t] - e0;
  const int ecnt = (int)(rowptr[rowBase + 32] - e0);
  for (int i=t; i<ecnt && i<EMAX; i+=128) lcol[i] = colh[e0+i];
  __syncthreads();

  // ---- phase 1: streaming pipelined gather ----
  {
    const int grp = t >> 5, c = t & 31;
    int cur = grp*8;                           // local row being accumulated
    const int curEnd = grp*8 + 8;
    f32x4 accv = {0.f,0.f,0.f,0.f};

    auto flushrow = [&](){
      uint32_t d = lrpl[cur+1] - lrpl[cur];
      float invd = 1.0f / (float)(d ? d : 1u);
      *(f32x4*)&smemA[cur][4*c] = accv * invd;
      accv = (f32x4){0.f,0.f,0.f,0.f};
      cur++;
    };

    const uint32_t kb = lrpl[grp*8], ke = lrpl[curEnd];
    auto run = [&](auto colAt){
      f32x4 v[8], w[8];
      #pragma unroll
      for (int j=0;j<8;++j){
        uint32_t kk = kb + j;
        int s = colAt(kk < ke ? kk : kb);
        v[j] = *(const f32x4*)(Xg + (size_t)s*DF + 4*c);
      }
      for (uint32_t k = kb; k < ke; k += 8){
        #pragma unroll
        for (int j=0;j<8;++j){                 // issue next chunk
          uint32_t kk = k + 8 + j;
          int s = colAt(kk < ke ? kk : k);
          w[j] = *(const f32x4*)(Xg + (size_t)s*DF + 4*c);
        }
        #pragma unroll
        for (int j=0;j<8;++j){                 // reduce current chunk
          uint32_t kk = k + j;
          if (kk < ke){
            while (lrpl[cur+1] <= kk) flushrow();
            accv += v[j];
          }
        }
        #pragma unroll
        for (int j=0;j<8;++j) v[j] = w[j];
      }
    };
    if (kb < ke){
      if (ecnt <= EMAX) run([&](uint32_t k){ return (int)lcol[k]; });
      else              run([&](uint32_t k){ return (int)colh[e0+k]; });
    }
    while (cur < curEnd) flushrow();           // trailing (incl. empty) rows
  }
  __syncthreads();

  // ---- phase 2: MFMA ----
  const int l = t & 63, wid = t >> 6;
  const int q = l >> 4, c16 = l & 15;
  const int arow = rowBase + wid*16 + c16;

  f32x4 own[8];                                // own row ks4..7 (issue early)
  #pragma unroll
  for (int ks4=0; ks4<4; ++ks4){
    const float* s = Xin + (size_t)arow*DF + ks4*32 + q*8;
    own[ks4*2]   = *(const f32x4*)s;
    own[ks4*2+1] = *(const f32x4*)(s+4);
  }

  f32x4 acc[8];
  #pragma unroll
  for (int ct=0; ct<8; ++ct) acc[ct] = (f32x4){0.f,0.f,0.f,0.f};

  #pragma unroll
  for (int ks=0; ks<8; ++ks){
    f32x4 A0, A1;
    if (ks < 4){
      const float* s = &smemA[wid*16 + c16][ks*32 + q*8];
      A0 = *(const f32x4*)s; A1 = *(const f32x4*)(s+4);
    } else {
      A0 = own[(ks-4)*2]; A1 = own[(ks-4)*2+1];
    }
    float v[8] = {A0.x,A0.y,A0.z,A0.w,A1.x,A1.y,A1.z,A1.w};
    bf16x8 ahi, alo;
    #pragma unroll
    for (int j=0;j<8;++j){
      unsigned short h, lo_; split2(v[j], h, lo_);
      ahi[j] = (short)h; alo[j] = (short)lo_;
    }
    const unsigned short* bp = Bpk + (size_t)ks*8192 + l*8;
    #pragma unroll
    for (int ct=0; ct<8; ++ct){
      bf16x8 bhi = *(const bf16x8*)(bp + ct*1024);
      bf16x8 blo = *(const bf16x8*)(bp + ct*1024 + 512);
      acc[ct] = __builtin_amdgcn_mfma_f32_16x16x32_bf16(ahi, bhi, acc[ct], 0,0,0);
      acc[ct] = __builtin_amdgcn_mfma_f32_16x16x32_bf16(ahi, blo, acc[ct], 0,0,0);
      acc[ct] = __builtin_amdgcn_mfma_f32_16x16x32_bf16(alo, bhi, acc[ct], 0,0,0);
    }
  }

  // ---- epilogue ----
  const int rowOut = rowBase + wid*16;
  if constexpr (LAYER==1){
    #pragma unroll
    for (int ct=0; ct<8; ++ct){
      int c = ct*16 + c16;
      float bv = bias[c];
      #pragma unroll
      for (int r=0; r<4; ++r){
        int grow = rowOut + q*4 + r;
        OUT[(size_t)grow*DF + c] = fmaxf(acc[ct][r] + bv, 0.f);
      }
    }
  } else {
    float ov[8][4];
    float pwv[8];
    float n2 = 0.f;
    #pragma unroll
    for (int ct=0; ct<8; ++ct){ pwv[ct] = pw[ct*16 + c16]; n2 += pwv[ct]*pwv[ct]; }
    n2 += __shfl_xor(n2,8,16); n2 += __shfl_xor(n2,4,16);
    n2 += __shfl_xor(n2,2,16); n2 += __shfl_xor(n2,1,16);
    float nrm = sqrtf(n2);
    #pragma unroll
    for (int ct=0; ct<8; ++ct){
      int c = ct*16 + c16;
      float bv = bias[c];
      #pragma unroll
      for (int r=0; r<4; ++r){
        int grow = rowOut + q*4 + r;
        float o = fmaxf(acc[ct][r] + bv, 0.f);
        OUT[(size_t)grow*DF + c] = o;
        ov[ct][r] = o;
      }
    }
    #pragma unroll
    for (int r=0; r<4; ++r){
      float p = 0.f;
      #pragma unroll
      for (int ct=0; ct<8; ++ct) p += ov[ct][r]*pwv[ct];
      p += __shfl_xor(p,8,16); p += __shfl_xor(p,4,16);
      p += __shfl_xor(p,2,16); p += __shfl_xor(p,1,16);
      if (c16 == 0) scores[rowOut + q*4 + r] = tanhf(p/nrm);
    }
  }
}

// ---------------- top-k via radix-select + pool + classifier ---------------
__global__ __launch_bounds__(1024) void k_topk(
    const float* __restrict__ scores, const float* __restrict__ H,
    const float* __restrict__ Wc1, const float* __restrict__ bc1,
    const float* __restrict__ Wc2, const float* __restrict__ bc2,
    float* __restrict__ out)
{
  __shared__ uint32_t keys[NNODE];            // 8KB monotone keys
  __shared__ uint32_t hist[64];
  __shared__ uint32_t wsum[16];               // block-scan wave sums
  __shared__ uint32_t sh_b, sh_rank, sh_cnt;
  __shared__ unsigned short selidx[KSEL+1];
  __shared__ float selval[KSEL+1];
  __shared__ float part[8*DF];
  __shared__ float emb[DF];
  __shared__ float hred[DF];

  const int t = threadIdx.x; const int b = blockIdx.x;
  const int lane = t & 63, wid = t >> 6;
  const float* sc = scores + b*NNODE;

  for (int i=t; i<NNODE; i+=1024) keys[i] = f2mono(sc[i]);
  __syncthreads();

  // ---- radix select: find threshold key T = 615th largest ----
  uint32_t prefix = 0, prefmask = 0, rank = KSEL, cntT = 0;
  #pragma unroll
  for (int lev=0; lev<6; ++lev){
    const int shift = (lev<5) ? (26 - 6*lev) : 0;
    const uint32_t bmask = (lev<5) ? 63u : 3u;
    if (t < 64) hist[t] = 0;
    __syncthreads();
    for (int i=t; i<NNODE; i+=1024){
      uint32_t k = keys[i];
      if ((k & prefmask) == prefix) atomicAdd(&hist[(k>>shift)&bmask], 1u);
    }
    __syncthreads();
    if (t < 64){
      uint32_t x = hist[t];
      #pragma unroll
      for (int off=1; off<64; off<<=1){        // inclusive suffix sum
        uint32_t y = __shfl_down(x, off, 64);
        if (t + off < 64) x += y;
      }
      uint32_t above = __shfl_down(x, 1, 64);
      if (t == 63) above = 0;
      if (above < rank && rank <= x){
        sh_b = (uint32_t)t; sh_rank = rank - above; sh_cnt = x - above;
      }
    }
    __syncthreads();
    prefix |= (sh_b << shift);
    prefmask |= (bmask << shift);
    rank = sh_rank; cntT = sh_cnt;
    __syncthreads();
  }
  const uint32_t T = prefix;
  const uint32_t m = rank;

  // ---- selection + compaction (block scans, shfl-based) ----
  uint32_t k0 = keys[2*t], k1 = keys[2*t+1];
  uint32_t eq0 = (k0 == T), eq1 = (k1 == T);
  uint32_t eqr0 = 0, eqr1 = 0;

  if (m != cntT){
    uint32_t v = eq0 + eq1, x = v;
    #pragma unroll
    for (int off=1; off<64; off<<=1){
      uint32_t y = __shfl_up(x, off, 64);
      if (lane >= off) x += y;
    }
    if (lane == 63) wsum[wid] = x;
    __syncthreads();
    if (wid == 0){
      uint32_t s = (lane < 16) ? wsum[lane] : 0;
      #pragma unroll
      for (int off=1; off<16; off<<=1){
        uint32_t y = __shfl_up(s, off, 64);
        if (lane >= off) s += y;
      }
      if (lane < 16) wsum[lane] = s;
    }
    __syncthreads();
    uint32_t excl = (wid ? wsum[wid-1] : 0) + x - v;
    eqr0 = excl; eqr1 = excl + eq0;
    __syncthreads();
  }

  uint32_t sel0 = (k0 > T) || (eq0 && eqr0 < m);
  uint32_t sel1 = (k1 > T) || (eq1 && eqr1 < m);
  {
    uint32_t v = sel0 + sel1, x = v;
    #pragma unroll
    for (int off=1; off<64; off<<=1){
      uint32_t y = __shfl_up(x, off, 64);
      if (lane >= off) x += y;
    }
    if (lane == 63) wsum[wid] = x;
    __syncthreads();
    if (wid == 0){
      uint32_t s = (lane < 16) ? wsum[lane] : 0;
      #pragma unroll
      for (int off=1; off<16; off<<=1){
        uint32_t y = __shfl_up(s, off, 64);
        if (lane >= off) s += y;
      }
      if (lane < 16) wsum[lane] = s;
    }
    __syncthreads();
    uint32_t excl = (wid ? wsum[wid-1] : 0) + x - v;
    if (sel0){ selidx[excl] = (unsigned short)(2*t);   selval[excl] = mono2f(k0); }
    if (sel1){ selidx[excl+sel0] = (unsigned short)(2*t+1); selval[excl+sel0] = mono2f(k1); }
  }
  __syncthreads();

  // ---- gated mean over the 615 selected rows (4-deep unrolled gather) ----
  const int pg = t >> 7, f = t & (DF-1);
  const float* Hb = H + (size_t)b*NNODE*DF;
  float accv = 0.f;
  int s2 = pg;
  for (; s2+24 < KSEL; s2 += 32){
    int i0=selidx[s2], i1=selidx[s2+8], i2=selidx[s2+16], i3=selidx[s2+24];
    float w0=selval[s2], w1=selval[s2+8], w2=selval[s2+16], w3=selval[s2+24];
    float v0=Hb[(size_t)i0*DF+f], v1=Hb[(size_t)i1*DF+f],
          v2=Hb[(size_t)i2*DF+f], v3=Hb[(size_t)i3*DF+f];
    accv += w0*v0 + w1*v1 + w2*v2 + w3*v3;
  }
  for (; s2<KSEL; s2+=8) accv += selval[s2]*Hb[(size_t)selidx[s2]*DF+f];
  part[pg*DF + f] = accv;
  __syncthreads();
  if (t < DF){
    float e = 0.f;
    for (int g2=0; g2<8; ++g2) e += part[g2*DF + t];
    emb[t] = e / (float)KSEL;
  }
  __syncthreads();
  if (t < DF){
    float hv = bc1[t];
    const float* wr = Wc1 + t*DF;
    for (int f2=0; f2<DF; ++f2) hv = fmaf(emb[f2], wr[f2], hv);
    hred[t] = fmaxf(hv, 0.f) * Wc2[t];
  }
  __syncthreads();
  if (t == 0){
    float o = bc2[0];
    for (int c2=0; c2<DF; ++c2) o += hred[c2];
    out[b] = o;
  }
}

// ---------------- launch ----------------
extern "C" void kernel_launch(void* const* d_in, const int* in_sizes, int n_in,
                              void* d_out, int out_size, void* d_ws, size_t ws_size,
                              hipStream_t stream)
{
  (void)in_sizes; (void)n_in; (void)out_size; (void)ws_size;
  const float* x   = (const float*)d_in[0];
  const int* esrc  = (const int*)d_in[1];
  const int* edst  = (const int*)d_in[2];
  const float* Wl1 = (const float*)d_in[3];
  const float* bl1 = (const float*)d_in[4];
  const float* Wr1 = (const float*)d_in[5];
  const float* Wl2 = (const float*)d_in[6];
  const float* bl2 = (const float*)d_in[7];
  const float* Wr2 = (const float*)d_in[8];
  const float* pw  = (const float*)d_in[9];
  const float* Wc1 = (const float*)d_in[10];
  const float* bc1 = (const float*)d_in[11];
  const float* Wc2 = (const float*)d_in[12];
  const float* bc2 = (const float*)d_in[13];
  float* out = (float*)d_out;

  char* ws = (char*)d_ws;                       // ~68 MB used
  float*    H1     = (float*)   (ws + 0);          // 32MB
  float*    H2     = (float*)   (ws + 33554432);   // 32MB
  uint32_t* deg    = (uint32_t*)(ws + 67108864);   // 256KB
  uint32_t* rowptr = (uint32_t*)(ws + 67371008);   // 65537 u32
  unsigned short* colh = (unsigned short*)(ws + 67633408); // 1MB u16
  float*    scores = (float*)   (ws + 68681728);   // 256KB
  unsigned short* Bpk = (unsigned short*)(ws + 68944128); // 256KB (2 layers)

  hipMemsetAsync(deg, 0, NT*sizeof(uint32_t), stream);

  // degree count (blocks 0..2047) + weight pack (blocks 2048..2079)
  k_deg    <<<ETOT/256 + 32, 256, 0, stream>>>(edst, deg, Wl1, Wr1, Wl2, Wr2, Bpk);
  k_scanG  <<<NB, 256, 0, stream>>>(deg, rowptr);
  k_scatter<<<ETOT/256, 256, 0, stream>>>(esrc, edst, rowptr, deg, colh);

  // fused layers: pipelined gather + mean + GEMM per block (r11 structure)
  k_sage<1><<<NT/32, 128, 0, stream>>>(x,  rowptr, colh, Bpk,         bl1,
                                       H1, nullptr, nullptr);
  k_sage<2><<<NT/32, 128, 0, stream>>>(H1, rowptr, colh, Bpk + 65536, bl2,
                                       H2, pw, scores);

  k_topk<<<NB, 1024, 0, stream>>>(scores, H2, Wc1, bc1, Wc2, bc2, out);
}